// Round 9
// baseline (767.611 us; speedup 1.0000x reference)
//
#include <hip/hip_runtime.h>

#define CIN   64
#define COUT  128
#define HH    512
#define WW    512
#define HW    (HH*WW)          // 262144

typedef __attribute__((ext_vector_type(8))) short  short8;   // 8 bf16
typedef __attribute__((ext_vector_type(4))) float  floatx4;

// ---------------- helpers ----------------

__device__ __forceinline__ unsigned short f2bf(float f) {
    unsigned u = __float_as_uint(f);
    u += 0x7fffu + ((u >> 16) & 1u);     // RNE
    return (unsigned short)(u >> 16);
}

// Wave-level LDS sync (FFT exchanges contained in 32 consecutive lanes).
__device__ __forceinline__ void wave_sync() {
    __builtin_amdgcn_wave_barrier();
    asm volatile("s_waitcnt lgkmcnt(0)" ::: "memory");
    __builtin_amdgcn_sched_barrier(0);
}
template<bool BLK> __device__ __forceinline__ void xsync() {
    if (BLK) __syncthreads(); else wave_sync();
}

// mirror-pairing column permutation: kw -> pos.  Mirror cols adjacent:
// pos0=kw0(self), pos1=kw256(self), pos 2j=kw j, pos 2j+1=kw 512-j.
__device__ __forceinline__ int posf(int col) {
    return (col == 0) ? 0 : (col == 256) ? 1
         : (col < 256) ? 2*col : 2*(512 - col) + 1;
}
__device__ __forceinline__ int dr6(int v) {            // 6-bit digit reversal (involution)
    return (v >> 3) + 8 * (v & 7);
}

// ---------------- prep: weights -> bf16 wt[9][co][ci] ----------------

__global__ __launch_bounds__(256) void k_wprep(
        const float* __restrict__ cw,          // [co][ci][3][3]
        unsigned short* __restrict__ wt)       // [9][128][64] bf16
{
    int i = blockIdx.x * 256 + threadIdx.x;    // grid 288*256 = 73728
    int tap = i >> 13;
    int co  = (i >> 6) & 127;
    int ci  = i & 63;
    wt[i] = f2bf(cw[(co * 64 + ci) * 9 + tap]);
}

// ---------------- prep: x fp32 [ci][h][w] -> bf16 xt[h][w][ci] ----------------

__global__ __launch_bounds__(256) void k_xprep(
        const float* __restrict__ x,
        unsigned short* __restrict__ xt)       // [512][512][64] bf16
{
    __shared__ unsigned short tile[64][72];    // [w][ci], 16B-aligned rows (144B)
    int t  = threadIdx.x;
    int h  = blockIdx.x >> 3;
    int w0 = (blockIdx.x & 7) << 6;
    int wl = t & 63;
#pragma unroll
    for (int it = 0; it < 16; ++it) {          // 4 ci-rows x 64 w per iter, coalesced
        int ci = (t >> 6) + 4 * it;
        tile[wl][ci] = f2bf(x[ci * HW + h * 512 + w0 + wl]);
    }
    __syncthreads();
#pragma unroll
    for (int it = 0; it < 2; ++it) {           // 64 rows x 8 segs of 16B, coalesced out
        int task = t + 256 * it;
        int w = task >> 3, seg = task & 7;
        *(short8*)&xt[((size_t)(h * 512 + w0 + w)) * 64 + seg * 8] =
            *(const short8*)&tile[w][seg * 8];
    }
}

// ---------------- prep: AB[p][pos][q] = {alpha,beta} pre-scaled ----------------
// alpha = (Ma[k][c]+Ma[-k][-c]+Mb[k][c]+Mb[-k][-c])*s4, beta same with minus.
// q = (8b+m)*32+w  <->  k = dr6(w+32b)+64m  (k_cols' exact read order).

__global__ __launch_bounds__(256) void k_AB(
        const float* __restrict__ mask,   // [128][k][col]
        float2* __restrict__ ab)          // [64][pos][512] {alpha,beta}
{
    __shared__ float SA[64][65];
    __shared__ float SB[64][65];
    int blk = blockIdx.x;                 // 64 p x 8 m(ktile) x 8 ct(coltile) = 4096
    int p  = blk >> 6;
    int m  = (blk >> 3) & 7;
    int ct = blk & 7;
    int k0 = m << 6, c0 = ct << 6;
    int t = threadIdx.x;
    int j = t & 63, i0 = t >> 6;
    const float* mA = mask + (size_t)(2*p) * HW;
    const float* mB = mA + HW;
    int mj = (512 - (c0 + j)) & 511;
#pragma unroll
    for (int it = 0; it < 16; ++it) {
        int i  = i0 + 4*it;
        int k1 = k0 + i;
        int mi = (512 - k1) & 511;
        SA[i][j] = mA[(size_t)k1*512 + c0 + j] + mA[(size_t)mi*512 + mj];
        SB[i][j] = mB[(size_t)k1*512 + c0 + j] + mB[(size_t)mi*512 + mj];
    }
    __syncthreads();
    const float s4 = 0.25f / 262144.0f;   // 1/4 combine * 1/N ifft scale
    int w = t & 31, jb = t >> 5;
#pragma unroll
    for (int pass = 0; pass < 8; ++pass) {
        int jj = jb + 8*pass;             // col within tile
        size_t base = ((size_t)p*512 + posf(c0 + jj))*512;
#pragma unroll
        for (int b = 0; b < 2; ++b) {
            int i = dr6(w + 32*b);        // k1 = k0 + i
            float sa = SA[i][jj], sb = SB[i][jj];
            ab[base + (8*b + m)*32 + w] = make_float2((sa+sb)*s4, (sa-sb)*s4);
        }
    }
}

// ---------------- conv: implicit GEMM, bf16 MFMA (verified R2) ----------------

__global__ __launch_bounds__(512) void k_conv(
        const unsigned short* __restrict__ xt,   // bf16 [h][w][ci]
        const unsigned short* __restrict__ wt,   // bf16 [9][co][ci]
        const float* __restrict__ bias,
        float* __restrict__ y)                   // fp32 [co][h][w]
{
    __shared__ __align__(16) unsigned short As[3][130][68];  // 53,040 B -> 3 blk/CU

    int b  = blockIdx.x;
    int h  = b >> 2;
    int w0 = (b & 3) << 7;
    int t  = threadIdx.x;
    int lane = t & 63, wv = t >> 6;
    int wm = wv >> 2, wn = wv & 3;
    int l15 = lane & 15, quad = lane >> 4;

    for (int idx = t; idx < 3 * 130 * 8; idx += 512) {
        int dy  = idx / 1040;
        int rem = idx - dy * 1040;
        int p   = rem >> 3, seg = rem & 7;
        int hp  = h + dy - 1;
        int wq  = w0 - 1 + p;
        short8 v = {0, 0, 0, 0, 0, 0, 0, 0};
        if ((unsigned)hp < 512u && (unsigned)wq < 512u)
            v = *(const short8*)&xt[((size_t)(hp * 512 + wq)) * 64 + seg * 8];
        *(short8*)&As[dy][p][seg * 8] = v;
    }
    __syncthreads();

    floatx4 acc[4][2];
#pragma unroll
    for (int mt = 0; mt < 4; ++mt)
#pragma unroll
        for (int nt = 0; nt < 2; ++nt) {
            floatx4 z = {0.f, 0.f, 0.f, 0.f};
            acc[mt][nt] = z;
        }

#pragma unroll
    for (int tap = 0; tap < 9; ++tap) {
        int dy = tap / 3, dx = tap - dy * 3;
        short8 bfr[2][2];
#pragma unroll
        for (int nt = 0; nt < 2; ++nt)
#pragma unroll
            for (int kc = 0; kc < 2; ++kc) {
                int co = wn * 32 + nt * 16 + l15;
                bfr[nt][kc] = *(const short8*)
                    &wt[(tap * 128 + co) * 64 + kc * 32 + quad * 8];
            }
#pragma unroll
        for (int kc = 0; kc < 2; ++kc) {
            int c0 = kc * 32 + quad * 8;
            short8 afr[4];
#pragma unroll
            for (int mt = 0; mt < 4; ++mt) {
                int row = wm * 64 + mt * 16 + l15 + dx;
                afr[mt] = *(const short8*)&As[dy][row][c0];
            }
#pragma unroll
            for (int mt = 0; mt < 4; ++mt)
#pragma unroll
                for (int nt = 0; nt < 2; ++nt)
                    acc[mt][nt] = __builtin_amdgcn_mfma_f32_16x16x32_bf16(
                        afr[mt], bfr[nt][kc], acc[mt][nt], 0, 0, 0);
        }
    }

#pragma unroll
    for (int nt = 0; nt < 2; ++nt) {
        int co = wn * 32 + nt * 16 + l15;
        float bv = bias[co];
#pragma unroll
        for (int mt = 0; mt < 4; ++mt) {
            floatx4 o = acc[mt][nt];
            o[0] += bv; o[1] += bv; o[2] += bv; o[3] += bv;
            int m = wm * 64 + mt * 16 + quad * 4;
            *(floatx4*)&y[co * HW + h * 512 + w0 + m] = o;
        }
    }
}

// ---------------- radix-8 register FFT (512 = 8^3), 32 threads/FFT ----------------
// FFT c on threads [32c..32c+32) (wave-contained, 2 FFTs per wave).
// LDS: one private row of 576 float2 per FFT, XOR-swizzled, bijective:
//   slot = c*576 + ((a + (a>>3)) ^ c).

#define FS 576

__device__ __forceinline__ int slotf(int c, int a) {
    return c * FS + ((a + (a >> 3)) ^ c);
}

__device__ __forceinline__ float2 cadd(float2 a, float2 b){ return make_float2(a.x+b.x, a.y+b.y); }
__device__ __forceinline__ float2 csub(float2 a, float2 b){ return make_float2(a.x-b.x, a.y-b.y); }

template<int DIR> __device__ __forceinline__ float2 twmul(float2 a, float2 t){
    return (DIR > 0) ? make_float2(a.x*t.x - a.y*t.y, a.x*t.y + a.y*t.x)
                     : make_float2(a.x*t.x + a.y*t.y, a.y*t.x - a.x*t.y);
}
template<int DIR> __device__ __forceinline__ float2 mulJ(float2 a){
    return (DIR > 0) ? make_float2(a.y, -a.x) : make_float2(-a.y, a.x);
}

#define RSQRT2 0.70710678118654752f

template<int DIR> __device__ __forceinline__ void dft8(float2* x){
    float2 a0 = cadd(x[0], x[4]), b0 = csub(x[0], x[4]);
    float2 a1 = cadd(x[1], x[5]), b1 = csub(x[1], x[5]);
    float2 a2 = cadd(x[2], x[6]), b2 = csub(x[2], x[6]);
    float2 a3 = cadd(x[3], x[7]), b3 = csub(x[3], x[7]);
    b1 = (DIR > 0) ? make_float2((b1.x + b1.y)*RSQRT2, (b1.y - b1.x)*RSQRT2)
                   : make_float2((b1.x - b1.y)*RSQRT2, (b1.y + b1.x)*RSQRT2);
    b2 = mulJ<DIR>(b2);
    b3 = (DIR > 0) ? make_float2((b3.y - b3.x)*RSQRT2, -(b3.x + b3.y)*RSQRT2)
                   : make_float2(-(b3.x + b3.y)*RSQRT2, (b3.x - b3.y)*RSQRT2);
    float2 c0 = cadd(a0, a2), d0 = csub(a0, a2);
    float2 c1 = cadd(a1, a3), d1 = mulJ<DIR>(csub(a1, a3));
    x[0] = cadd(c0, c1); x[4] = csub(c0, c1);
    x[2] = cadd(d0, d1); x[6] = csub(d0, d1);
    float2 e0 = cadd(b0, b2), f0 = csub(b0, b2);
    float2 e1 = cadd(b1, b3), f1 = mulJ<DIR>(csub(b1, b3));
    x[1] = cadd(e0, e1); x[5] = csub(e0, e1);
    x[3] = cadd(f0, f1); x[7] = csub(f0, f1);
}

// Forward DIF. Entry: X[b][r] = x[g_b + 64 r], g_b = w + 32 b (natural).
// Exit: X[b][m] = X^(K) at K = dr6(v) + 64*m, v = w + 32 b.
template<bool BLK>
__device__ __forceinline__ void fft512_fwd(float2 X[2][8], float2* buf,
                                           const float2* tw, int w, int c) {
#pragma unroll
    for (int b = 0; b < 2; ++b) {                      // P0 (stride 64)
        dft8<1>(X[b]);
        int g = w + 32*b;
#pragma unroll
        for (int k = 1; k < 8; ++k) X[b][k] = twmul<1>(X[b][k], tw[g*k]);
    }
#pragma unroll
    for (int b = 0; b < 2; ++b) {                      // E0 write: a = k*64 + g
        int g = w + 32*b;
#pragma unroll
        for (int k = 0; k < 8; ++k) buf[slotf(c, k*64 + g)] = X[b][k];
    }
    xsync<BLK>();
#pragma unroll
    for (int b = 0; b < 2; ++b) {                      // E0 read
        int u = w + 32*b; int bs = (u >> 3)*64 + (u & 7);
#pragma unroll
        for (int g2 = 0; g2 < 8; ++g2) X[b][g2] = buf[slotf(c, bs + 8*g2)];
    }
#pragma unroll
    for (int b = 0; b < 2; ++b) {                      // P1 (stride 8)
        dft8<1>(X[b]);
        int g1 = (w + 32*b) & 7;
#pragma unroll
        for (int k = 1; k < 8; ++k) X[b][k] = twmul<1>(X[b][k], tw[8*g1*k]);
    }
    xsync<BLK>();                                      // E0-read done before E1-write
#pragma unroll
    for (int b = 0; b < 2; ++b) {                      // E1 write
        int u = w + 32*b; int bs = (u >> 3)*64 + (u & 7);
#pragma unroll
        for (int k = 0; k < 8; ++k) buf[slotf(c, bs + 8*k)] = X[b][k];
    }
    xsync<BLK>();
#pragma unroll
    for (int b = 0; b < 2; ++b) {                      // E1 read: a = 8*v + g1
        int v = w + 32*b;
#pragma unroll
        for (int g1 = 0; g1 < 8; ++g1) X[b][g1] = buf[slotf(c, 8*v + g1)];
    }
#pragma unroll
    for (int b = 0; b < 2; ++b) dft8<1>(X[b]);         // P2 (no twiddle)
}

// Inverse DIT. Entry: X[b][m] at digit-reversed residency (as fwd exit).
// Exit: X[b][r] = x[g_b + 64 r] (natural order, unscaled).
template<bool BLK>
__device__ __forceinline__ void fft512_inv(float2 X[2][8], float2* buf,
                                           const float2* tw, int w, int c) {
#pragma unroll
    for (int b = 0; b < 2; ++b) dft8<-1>(X[b]);        // Q0 (regs only)
    xsync<BLK>();                                      // prior own-row buf reads done
#pragma unroll
    for (int b = 0; b < 2; ++b) {                      // E1' write: a = 8*v + g1
        int v = w + 32*b;
#pragma unroll
        for (int g1 = 0; g1 < 8; ++g1) buf[slotf(c, 8*v + g1)] = X[b][g1];
    }
    xsync<BLK>();
#pragma unroll
    for (int b = 0; b < 2; ++b) {                      // E1' read
        int u = w + 32*b; int bs = (u >> 3)*64 + (u & 7);
#pragma unroll
        for (int k = 0; k < 8; ++k) X[b][k] = buf[slotf(c, bs + 8*k)];
    }
#pragma unroll
    for (int b = 0; b < 2; ++b) {                      // Q1: conj-tw then idft8
        int g1 = (w + 32*b) & 7;
#pragma unroll
        for (int k = 1; k < 8; ++k) X[b][k] = twmul<-1>(X[b][k], tw[8*g1*k]);
        dft8<-1>(X[b]);
    }
    xsync<BLK>();                                      // E1'-read done before E0'-write
#pragma unroll
    for (int b = 0; b < 2; ++b) {                      // E0' write
        int u = w + 32*b; int bs = (u >> 3)*64 + (u & 7);
#pragma unroll
        for (int g2 = 0; g2 < 8; ++g2) buf[slotf(c, bs + 8*g2)] = X[b][g2];
    }
    xsync<BLK>();
#pragma unroll
    for (int b = 0; b < 2; ++b) {                      // E0' read: a = k*64 + g
        int g = w + 32*b;
#pragma unroll
        for (int k = 0; k < 8; ++k) X[b][k] = buf[slotf(c, k*64 + g)];
    }
#pragma unroll
    for (int b = 0; b < 2; ++b) {                      // Q2: conj-tw then idft8
        int g = w + 32*b;
#pragma unroll
        for (int k = 1; k < 8; ++k) X[b][k] = twmul<-1>(X[b][k], tw[g*k]);
        dft8<-1>(X[b]);
    }
}

template<int NT>
__device__ __forceinline__ void build_tw(float2* tw, int t) {
    const float a0 = -6.283185307179586f / 512.0f;
#pragma unroll
    for (int i = 0; i < 512/NT; ++i) {
        float s, c;
        __sincosf(a0 * (float)(t + NT*i), &s, &c);
        tw[t + NT*i] = make_float2(c, s);
    }
}

// ---------------- channel-paired FFT pipeline, permuted-transposed spectrum ----
// ZTP[p][pos][row], pos = posf(kw): mirror columns adjacent -> k_cols blocks
// touch one contiguous 32-KB region (stage-in, stage-out, AB reads).

// ---- rows forward: two real channels -> ZTP (512 thr, 16 rows/block) ----
__global__ __launch_bounds__(512) void k_rows_fwd_pair(
        const float* __restrict__ y,      // [128][512][512]
        float2* __restrict__ Z)           // ZTP [64][pos][row]
{
    __shared__ float2 buf[16 * FS];       // 73,728 B
    __shared__ float2 tw[512];
    int t = threadIdx.x;
    build_tw<512>(tw, t);
    int c = t >> 5, w = t & 31;           // 16 FFT rows, 32 thr each
    int p = blockIdx.x >> 5, r0 = (blockIdx.x & 31) << 4;
    const float* yA = y + (size_t)(2*p) * HW + (size_t)(r0 + c) * 512;
    const float* yB = yA + HW;

    float2 X[2][8];
#pragma unroll
    for (int b = 0; b < 2; ++b)
#pragma unroll
        for (int r = 0; r < 8; ++r) {
            int off = w + 32*b + 64*r;
            X[b][r] = make_float2(yA[off], yB[off]);   // direct, 128B/group
        }
    __syncthreads();                                  // tw ready
    fft512_fwd<false>(X, buf, tw, w, c);

    wave_sync();                                      // own-row E1-reads done
#pragma unroll
    for (int b = 0; b < 2; ++b) {                     // publish natural order
        int kb = dr6(w + 32*b);
#pragma unroll
        for (int m = 0; m < 8; ++m) buf[slotf(c, kb + 64*m)] = X[b][m];
    }
    __syncthreads();                                  // cross-wave stage-out
    size_t zb = (size_t)p * HW + r0;
    for (int it = 0; it < 16; ++it) {                 // transposed+permuted: 128B/col
        int n = t + 512*it;
        int col = n >> 4, rr = n & 15;
        Z[zb + (size_t)posf(col)*512 + rr] = buf[slotf(rr, col)];
    }
}

// ---- cols: fwd FFT along H, Hermitian mask-combine, inv FFT along H ----
// 256 thr, 8 adjacent pos/block = contiguous 32-KB Z region; AB contiguous.
__global__ __launch_bounds__(256, 4) void k_cols_pair(
        float2* __restrict__ Z,           // ZTP [64][pos][row], in place
        const float2* __restrict__ ab)    // AB [64][pos][512] {alpha,beta}
{
    __shared__ float2 buf[8 * FS];        // 36,864 B
    __shared__ float2 tw[512];
    int t = threadIdx.x;
    build_tw<256>(tw, t);
    int c = t >> 5, w = t & 31;
    int p = blockIdx.x >> 6, g = blockIdx.x & 63;
    int cm = (g == 0 && c < 2) ? c : (c ^ 1);         // mirror col is adjacent pos
    size_t zblk = (size_t)p * HW + (size_t)(8*g) * 512;   // contiguous 4096 float2
    const float2* abp = ab + ((size_t)p*512 + 8*g + c)*512;

    for (int it = 0; it < 16; ++it) {                 // sequential stage-in: 32 KB
        int n = t + 256*it;
        buf[slotf(n >> 9, n & 511)] = Z[zblk + n];
    }
    float2 AB[2][8];
#pragma unroll
    for (int b = 0; b < 2; ++b)                       // coalesced 256B reads
#pragma unroll
        for (int m = 0; m < 8; ++m)
            AB[b][m] = abp[(8*b + m)*32 + w];
    __syncthreads();                                  // stage + tw ready

    float2 X[2][8];
#pragma unroll
    for (int b = 0; b < 2; ++b)
#pragma unroll
        for (int r = 0; r < 8; ++r)
            X[b][r] = buf[slotf(c, w + 32*b + 64*r)];
    wave_sync();                                      // own-row gather before E0 writes
    fft512_fwd<false>(X, buf, tw, w, c);

    wave_sync();                                      // own-row E1-reads done
#pragma unroll
    for (int b = 0; b < 2; ++b) {                     // publish spectra for mirror gather
        int kb = dr6(w + 32*b);
#pragma unroll
        for (int m = 0; m < 8; ++m) buf[slotf(c, kb + 64*m)] = X[b][m];
    }
    __syncthreads();                                  // mirror row is cross-wave

#pragma unroll
    for (int b = 0; b < 2; ++b) {
        int kb = dr6(w + 32*b);
#pragma unroll
        for (int m = 0; m < 8; ++m) {
            int k1  = kb + 64*m;
            int mk1 = (512 - k1) & 511;
            float2 P = X[b][m];
            float2 Q = buf[slotf(cm, mk1)];            // Zhat[-k1, mirror col]
            float alpha = AB[b][m].x, beta = AB[b][m].y;   // pre-scaled
            X[b][m] = make_float2(alpha * P.x + beta * Q.x,
                                  alpha * P.y - beta * Q.y);
        }
    }
    __syncthreads();                                  // mirror reads of row c done
    fft512_inv<false>(X, buf, tw, w, c);
    wave_sync();                                      // own-row E0'-reads done
#pragma unroll
    for (int b = 0; b < 2; ++b)                       // publish natural for stage-out
#pragma unroll
        for (int r = 0; r < 8; ++r)
            buf[slotf(c, w + 32*b + 64*r)] = X[b][r];
    __syncthreads();                                  // cross-wave stage-out
    for (int it = 0; it < 16; ++it) {                 // sequential stage-out: 32 KB
        int n = t + 256*it;
        Z[zblk + n] = buf[slotf(n >> 9, n & 511)];
    }
}

// ---- rows inverse: ZTP -> two real output channels (512 thr, 16 rows) ----
__global__ __launch_bounds__(512) void k_rows_inv_pair(
        const float2* __restrict__ Z,     // ZTP [64][pos][row]
        float* __restrict__ out)          // [128][512][512]
{
    __shared__ float2 buf[16 * FS];
    __shared__ float2 tw[512];
    int t = threadIdx.x;
    build_tw<512>(tw, t);
    int c = t >> 5, w = t & 31;
    int p = blockIdx.x >> 5, r0 = (blockIdx.x & 31) << 4;
    size_t zb = (size_t)p * HW + r0;

    for (int it = 0; it < 16; ++it) {                 // permuted stage-in: 128B/col
        int n = t + 512*it;
        int col = n >> 4, rr = n & 15;
        buf[slotf(rr, col)] = Z[zb + (size_t)posf(col)*512 + rr];
    }
    __syncthreads();                                  // stage + tw ready

    float2 X[2][8];
#pragma unroll
    for (int b = 0; b < 2; ++b) {                     // gather digit-rev residency
        int kb = dr6(w + 32*b);
#pragma unroll
        for (int m = 0; m < 8; ++m) X[b][m] = buf[slotf(c, kb + 64*m)];
    }
    fft512_inv<false>(X, buf, tw, w, c);              // internal wave_sync orders gather

    float* oA = out + (size_t)(2*p) * HW + (size_t)(r0 + c) * 512;
    float* oB = oA + HW;
#pragma unroll
    for (int b = 0; b < 2; ++b)
#pragma unroll
        for (int r = 0; r < 8; ++r) {
            int off = w + 32*b + 64*r;
            oA[off] = X[b][r].x;                      // direct, 128B/group
            oB[off] = X[b][r].y;
        }
}

// ---------------- launch ----------------

extern "C" void kernel_launch(void* const* d_in, const int* in_sizes, int n_in,
                              void* d_out, int out_size, void* d_ws, size_t ws_size,
                              hipStream_t stream) {
    const float* x    = (const float*)d_in[0];
    const float* cw   = (const float*)d_in[1];
    const float* cb   = (const float*)d_in[2];
    const float* mask = (const float*)d_in[3];

    float*  outRe = (float*)d_out;       // y -> AB -> final out (time-sliced)
    float2* ZTP   = (float2*)d_ws;       // permuted transposed spectrum (134 MB)
    float2* AB    = (float2*)d_out;      // 64*512*512*8 B = exactly out_size

    // xt/wt occupy ws before ZTP is first written (dead after conv).
    unsigned short* xt = (unsigned short*)d_ws;                       // 33,554,432 B
    unsigned short* wt = (unsigned short*)d_ws + (size_t)HW * 64;     //    147,456 B

    k_wprep<<<288, 256, 0, stream>>>(cw, wt);
    k_xprep<<<4096, 256, 0, stream>>>(x, xt);
    k_conv<<<2048, 512, 0, stream>>>(xt, wt, cb, outRe);
    k_rows_fwd_pair<<<2048, 512, 0, stream>>>(outRe, ZTP);  // reads y, frees d_out
    k_AB<<<4096, 256, 0, stream>>>(mask, AB);               // AB into d_out
    k_cols_pair<<<4096, 256, 0, stream>>>(ZTP, AB);
    k_rows_inv_pair<<<2048, 512, 0, stream>>>(ZTP, outRe);  // overwrites AB
}

// Round 10
// 583.152 us; speedup vs baseline: 1.3163x; 1.3163x over previous
//
#include <hip/hip_runtime.h>

#define CIN   64
#define COUT  128
#define HH    512
#define WW    512
#define HW    (HH*WW)          // 262144

typedef __attribute__((ext_vector_type(8))) short  short8;   // 8 bf16
typedef __attribute__((ext_vector_type(4))) float  floatx4;

// ---------------- helpers ----------------

__device__ __forceinline__ unsigned short f2bf(float f) {
    unsigned u = __float_as_uint(f);
    u += 0x7fffu + ((u >> 16) & 1u);     // RNE
    return (unsigned short)(u >> 16);
}

// Wave-level LDS sync (FFT exchanges contained in 32 consecutive lanes).
__device__ __forceinline__ void wave_sync() {
    __builtin_amdgcn_wave_barrier();
    asm volatile("s_waitcnt lgkmcnt(0)" ::: "memory");
    __builtin_amdgcn_sched_barrier(0);
}
template<bool BLK> __device__ __forceinline__ void xsync() {
    if (BLK) __syncthreads(); else wave_sync();
}

__device__ __forceinline__ int dr6(int v) {            // 6-bit digit reversal 8x8
    return (v >> 3) + 8 * (v & 7);
}

// ---------------- prep: weights -> bf16 wt[9][co][ci] ----------------

__global__ __launch_bounds__(256) void k_wprep(
        const float* __restrict__ cw,          // [co][ci][3][3]
        unsigned short* __restrict__ wt)       // [9][128][64] bf16
{
    int i = blockIdx.x * 256 + threadIdx.x;    // grid 288*256 = 73728
    int tap = i >> 13;
    int co  = (i >> 6) & 127;
    int ci  = i & 63;
    wt[i] = f2bf(cw[(co * 64 + ci) * 9 + tap]);
}

// ---------------- prep: x fp32 [ci][h][w] -> bf16 xt[h][w][ci] ----------------

__global__ __launch_bounds__(256) void k_xprep(
        const float* __restrict__ x,
        unsigned short* __restrict__ xt)       // [512][512][64] bf16
{
    __shared__ unsigned short tile[64][72];    // [w][ci], 16B-aligned rows (144B)
    int t  = threadIdx.x;
    int h  = blockIdx.x >> 3;
    int w0 = (blockIdx.x & 7) << 6;
    int wl = t & 63;
#pragma unroll
    for (int it = 0; it < 16; ++it) {          // 4 ci-rows x 64 w per iter, coalesced
        int ci = (t >> 6) + 4 * it;
        tile[wl][ci] = f2bf(x[ci * HW + h * 512 + w0 + wl]);
    }
    __syncthreads();
#pragma unroll
    for (int it = 0; it < 2; ++it) {           // 64 rows x 8 segs of 16B, coalesced out
        int task = t + 256 * it;
        int w = task >> 3, seg = task & 7;
        *(short8*)&xt[((size_t)(h * 512 + w0 + w)) * 64 + seg * 8] =
            *(const short8*)&tile[w][seg * 8];
    }
}

// ---------------- prep: maskT2[ch][col][k] = M[k][col] + M[-k][-col] ----------------

__global__ __launch_bounds__(256) void k_maskT2(
        const float* __restrict__ mask,   // [ch][k][col]
        float* __restrict__ mt)           // [ch][col][k], symmetrized
{
    __shared__ float t1[64][65];
    __shared__ float t2[64][65];
    int b  = blockIdx.x;                  // 128 ch x 8 ktile x 8 ctile = 8192
    int ch = b >> 6;
    int k0 = ((b >> 3) & 7) << 6;
    int c0 = (b & 7) << 6;
    int t  = threadIdx.x;
    int j  = t & 63, i0 = t >> 6;
    const float* mch = mask + (size_t)ch * HW;
#pragma unroll
    for (int it = 0; it < 16; ++it) {
        int i  = i0 + 4 * it;
        int mi = (512 - (k0 + i)) & 511;
        int mj = (512 - (c0 + j)) & 511;
        t1[i][j] = mch[(size_t)(k0 + i) * 512 + (c0 + j)];
        t2[i][j] = mch[(size_t)mi * 512 + mj];
    }
    __syncthreads();
    float* och = mt + (size_t)ch * HW;
#pragma unroll
    for (int it = 0; it < 16; ++it) {
        int jj = i0 + 4 * it;             // col within tile; k index = j (lane)
        och[(size_t)(c0 + jj) * 512 + k0 + j] = t1[j][jj] + t2[j][jj];
    }
}

// ---------------- conv: implicit GEMM, bf16 MFMA (verified R2) ----------------

__global__ __launch_bounds__(512) void k_conv(
        const unsigned short* __restrict__ xt,   // bf16 [h][w][ci]
        const unsigned short* __restrict__ wt,   // bf16 [9][co][ci]
        const float* __restrict__ bias,
        float* __restrict__ y)                   // fp32 [co][h][w]
{
    __shared__ __align__(16) unsigned short As[3][130][68];  // 53,040 B -> 3 blk/CU

    int b  = blockIdx.x;
    int h  = b >> 2;
    int w0 = (b & 3) << 7;
    int t  = threadIdx.x;
    int lane = t & 63, wv = t >> 6;
    int wm = wv >> 2, wn = wv & 3;
    int l15 = lane & 15, quad = lane >> 4;

    for (int idx = t; idx < 3 * 130 * 8; idx += 512) {
        int dy  = idx / 1040;
        int rem = idx - dy * 1040;
        int p   = rem >> 3, seg = rem & 7;
        int hp  = h + dy - 1;
        int wq  = w0 - 1 + p;
        short8 v = {0, 0, 0, 0, 0, 0, 0, 0};
        if ((unsigned)hp < 512u && (unsigned)wq < 512u)
            v = *(const short8*)&xt[((size_t)(hp * 512 + wq)) * 64 + seg * 8];
        *(short8*)&As[dy][p][seg * 8] = v;
    }
    __syncthreads();

    floatx4 acc[4][2];
#pragma unroll
    for (int mt = 0; mt < 4; ++mt)
#pragma unroll
        for (int nt = 0; nt < 2; ++nt) {
            floatx4 z = {0.f, 0.f, 0.f, 0.f};
            acc[mt][nt] = z;
        }

#pragma unroll
    for (int tap = 0; tap < 9; ++tap) {
        int dy = tap / 3, dx = tap - dy * 3;
        short8 bfr[2][2];
#pragma unroll
        for (int nt = 0; nt < 2; ++nt)
#pragma unroll
            for (int kc = 0; kc < 2; ++kc) {
                int co = wn * 32 + nt * 16 + l15;
                bfr[nt][kc] = *(const short8*)
                    &wt[(tap * 128 + co) * 64 + kc * 32 + quad * 8];
            }
#pragma unroll
        for (int kc = 0; kc < 2; ++kc) {
            int c0 = kc * 32 + quad * 8;
            short8 afr[4];
#pragma unroll
            for (int mt = 0; mt < 4; ++mt) {
                int row = wm * 64 + mt * 16 + l15 + dx;
                afr[mt] = *(const short8*)&As[dy][row][c0];
            }
#pragma unroll
            for (int mt = 0; mt < 4; ++mt)
#pragma unroll
                for (int nt = 0; nt < 2; ++nt)
                    acc[mt][nt] = __builtin_amdgcn_mfma_f32_16x16x32_bf16(
                        afr[mt], bfr[nt][kc], acc[mt][nt], 0, 0, 0);
        }
    }

#pragma unroll
    for (int nt = 0; nt < 2; ++nt) {
        int co = wn * 32 + nt * 16 + l15;
        float bv = bias[co];
#pragma unroll
        for (int mt = 0; mt < 4; ++mt) {
            floatx4 o = acc[mt][nt];
            o[0] += bv; o[1] += bv; o[2] += bv; o[3] += bv;
            int m = wm * 64 + mt * 16 + quad * 4;
            *(floatx4*)&y[co * HW + h * 512 + w0 + m] = o;
        }
    }
}

// ---------------- radix-8 register FFT (512 = 8^3), 32 threads/FFT ----------------
// FFT c on threads [32c..32c+32) (wave-contained, 2 FFTs per wave).
// LDS: one private row of 576 float2 per FFT, XOR-swizzled, bijective:
//   slot = c*576 + ((a + (a>>3)) ^ c).

#define FS 576

__device__ __forceinline__ int slotf(int c, int a) {
    return c * FS + ((a + (a >> 3)) ^ c);
}

__device__ __forceinline__ float2 cadd(float2 a, float2 b){ return make_float2(a.x+b.x, a.y+b.y); }
__device__ __forceinline__ float2 csub(float2 a, float2 b){ return make_float2(a.x-b.x, a.y-b.y); }

template<int DIR> __device__ __forceinline__ float2 twmul(float2 a, float2 t){
    return (DIR > 0) ? make_float2(a.x*t.x - a.y*t.y, a.x*t.y + a.y*t.x)
                     : make_float2(a.x*t.x + a.y*t.y, a.y*t.x - a.x*t.y);
}
template<int DIR> __device__ __forceinline__ float2 mulJ(float2 a){
    return (DIR > 0) ? make_float2(a.y, -a.x) : make_float2(-a.y, a.x);
}

#define RSQRT2 0.70710678118654752f

template<int DIR> __device__ __forceinline__ void dft8(float2* x){
    float2 a0 = cadd(x[0], x[4]), b0 = csub(x[0], x[4]);
    float2 a1 = cadd(x[1], x[5]), b1 = csub(x[1], x[5]);
    float2 a2 = cadd(x[2], x[6]), b2 = csub(x[2], x[6]);
    float2 a3 = cadd(x[3], x[7]), b3 = csub(x[3], x[7]);
    b1 = (DIR > 0) ? make_float2((b1.x + b1.y)*RSQRT2, (b1.y - b1.x)*RSQRT2)
                   : make_float2((b1.x - b1.y)*RSQRT2, (b1.y + b1.x)*RSQRT2);
    b2 = mulJ<DIR>(b2);
    b3 = (DIR > 0) ? make_float2((b3.y - b3.x)*RSQRT2, -(b3.x + b3.y)*RSQRT2)
                   : make_float2(-(b3.x + b3.y)*RSQRT2, (b3.x - b3.y)*RSQRT2);
    float2 c0 = cadd(a0, a2), d0 = csub(a0, a2);
    float2 c1 = cadd(a1, a3), d1 = mulJ<DIR>(csub(a1, a3));
    x[0] = cadd(c0, c1); x[4] = csub(c0, c1);
    x[2] = cadd(d0, d1); x[6] = csub(d0, d1);
    float2 e0 = cadd(b0, b2), f0 = csub(b0, b2);
    float2 e1 = cadd(b1, b3), f1 = mulJ<DIR>(csub(b1, b3));
    x[1] = cadd(e0, e1); x[5] = csub(e0, e1);
    x[3] = cadd(f0, f1); x[7] = csub(f0, f1);
}

// Forward DIF. Entry: X[b][r] = x[g_b + 64 r], g_b = w + 32 b (natural).
// Exit: X[b][m] = X^(K) at K = dr6(v) + 64*m, v = w + 32 b.
template<bool BLK>
__device__ __forceinline__ void fft512_fwd(float2 X[2][8], float2* buf,
                                           const float2* tw, int w, int c) {
#pragma unroll
    for (int b = 0; b < 2; ++b) {                      // P0 (stride 64)
        dft8<1>(X[b]);
        int g = w + 32*b;
#pragma unroll
        for (int k = 1; k < 8; ++k) X[b][k] = twmul<1>(X[b][k], tw[g*k]);
    }
#pragma unroll
    for (int b = 0; b < 2; ++b) {                      // E0 write: a = k*64 + g
        int g = w + 32*b;
#pragma unroll
        for (int k = 0; k < 8; ++k) buf[slotf(c, k*64 + g)] = X[b][k];
    }
    xsync<BLK>();
#pragma unroll
    for (int b = 0; b < 2; ++b) {                      // E0 read
        int u = w + 32*b; int bs = (u >> 3)*64 + (u & 7);
#pragma unroll
        for (int g2 = 0; g2 < 8; ++g2) X[b][g2] = buf[slotf(c, bs + 8*g2)];
    }
#pragma unroll
    for (int b = 0; b < 2; ++b) {                      // P1 (stride 8)
        dft8<1>(X[b]);
        int g1 = (w + 32*b) & 7;
#pragma unroll
        for (int k = 1; k < 8; ++k) X[b][k] = twmul<1>(X[b][k], tw[8*g1*k]);
    }
    xsync<BLK>();                                      // E0-read done before E1-write
#pragma unroll
    for (int b = 0; b < 2; ++b) {                      // E1 write
        int u = w + 32*b; int bs = (u >> 3)*64 + (u & 7);
#pragma unroll
        for (int k = 0; k < 8; ++k) buf[slotf(c, bs + 8*k)] = X[b][k];
    }
    xsync<BLK>();
#pragma unroll
    for (int b = 0; b < 2; ++b) {                      // E1 read: a = 8*v + g1
        int v = w + 32*b;
#pragma unroll
        for (int g1 = 0; g1 < 8; ++g1) X[b][g1] = buf[slotf(c, 8*v + g1)];
    }
#pragma unroll
    for (int b = 0; b < 2; ++b) dft8<1>(X[b]);         // P2 (no twiddle)
}

// Inverse DIT. Entry: X[b][m] at digit-reversed residency (as fwd exit).
// Exit: X[b][r] = x[g_b + 64 r] (natural order, unscaled).
template<bool BLK>
__device__ __forceinline__ void fft512_inv(float2 X[2][8], float2* buf,
                                           const float2* tw, int w, int c) {
#pragma unroll
    for (int b = 0; b < 2; ++b) dft8<-1>(X[b]);        // Q0 (regs only)
    xsync<BLK>();                                      // prior own-row buf reads done
#pragma unroll
    for (int b = 0; b < 2; ++b) {                      // E1' write: a = 8*v + g1
        int v = w + 32*b;
#pragma unroll
        for (int g1 = 0; g1 < 8; ++g1) buf[slotf(c, 8*v + g1)] = X[b][g1];
    }
    xsync<BLK>();
#pragma unroll
    for (int b = 0; b < 2; ++b) {                      // E1' read
        int u = w + 32*b; int bs = (u >> 3)*64 + (u & 7);
#pragma unroll
        for (int k = 0; k < 8; ++k) X[b][k] = buf[slotf(c, bs + 8*k)];
    }
#pragma unroll
    for (int b = 0; b < 2; ++b) {                      // Q1: conj-tw then idft8
        int g1 = (w + 32*b) & 7;
#pragma unroll
        for (int k = 1; k < 8; ++k) X[b][k] = twmul<-1>(X[b][k], tw[8*g1*k]);
        dft8<-1>(X[b]);
    }
    xsync<BLK>();                                      // E1'-read done before E0'-write
#pragma unroll
    for (int b = 0; b < 2; ++b) {                      // E0' write
        int u = w + 32*b; int bs = (u >> 3)*64 + (u & 7);
#pragma unroll
        for (int g2 = 0; g2 < 8; ++g2) buf[slotf(c, bs + 8*g2)] = X[b][g2];
    }
    xsync<BLK>();
#pragma unroll
    for (int b = 0; b < 2; ++b) {                      // E0' read: a = k*64 + g
        int g = w + 32*b;
#pragma unroll
        for (int k = 0; k < 8; ++k) X[b][k] = buf[slotf(c, k*64 + g)];
    }
#pragma unroll
    for (int b = 0; b < 2; ++b) {                      // Q2: conj-tw then idft8
        int g = w + 32*b;
#pragma unroll
        for (int k = 1; k < 8; ++k) X[b][k] = twmul<-1>(X[b][k], tw[g*k]);
        dft8<-1>(X[b]);
    }
}

template<int NT>
__device__ __forceinline__ void build_tw(float2* tw, int t) {
    const float a0 = -6.283185307179586f / 512.0f;
#pragma unroll
    for (int i = 0; i < 512/NT; ++i) {
        float s, c;
        __sincosf(a0 * (float)(t + NT*i), &s, &c);
        tw[t + NT*i] = make_float2(c, s);
    }
}

// ---------------- channel-paired FFT pipeline, transposed spectrum ----------------
// ZT[p][col][row]; all global I/O full-line coalesced (>=128B chunks).
// k_cols uses R4's verified-clean geometry: 2 blk/CU, 64KB/block, grid 2048.

// ---- rows forward: two real channels -> ZT (512 thr, 16 rows/block) ----
__global__ __launch_bounds__(512) void k_rows_fwd_pair(
        const float* __restrict__ y,      // [128][512][512]
        float2* __restrict__ Z)           // ZT [64][col][row]
{
    __shared__ float2 buf[16 * FS];       // 73,728 B
    __shared__ float2 tw[512];
    int t = threadIdx.x;
    build_tw<512>(tw, t);
    int c = t >> 5, w = t & 31;           // 16 FFT rows, 32 thr each
    int p = blockIdx.x >> 5, r0 = (blockIdx.x & 31) << 4;
    const float* yA = y + (size_t)(2*p) * HW + (size_t)(r0 + c) * 512;
    const float* yB = yA + HW;

    float2 X[2][8];
#pragma unroll
    for (int b = 0; b < 2; ++b)
#pragma unroll
        for (int r = 0; r < 8; ++r) {
            int off = w + 32*b + 64*r;
            X[b][r] = make_float2(yA[off], yB[off]);   // direct, 128B/group
        }
    __syncthreads();                                  // tw ready
    fft512_fwd<false>(X, buf, tw, w, c);

    wave_sync();                                      // own-row E1-reads done
#pragma unroll
    for (int b = 0; b < 2; ++b) {                     // publish natural order
        int kb = dr6(w + 32*b);
#pragma unroll
        for (int m = 0; m < 8; ++m) buf[slotf(c, kb + 64*m)] = X[b][m];
    }
    __syncthreads();                                  // cross-wave stage-out
    size_t zb = (size_t)p * HW + r0;
    for (int it = 0; it < 16; ++it) {                 // transposed stage-out: 128B/col
        int n = t + 512*it;
        int col = n >> 4, rr = n & 15;
        Z[zb + (size_t)col*512 + rr] = buf[slotf(rr, col)];
    }
}

// mirror-closed column groups of 16 (R4-verified):
//  g=0 : {0..7, 256, 505..511};  g>=1: {8g..8g+7} U {512-8g-7..512-8g}
__device__ __forceinline__ int col_of(int g, int j) {
    if (g == 0) return (j < 8) ? j : (j == 8 ? 256 : 496 + j);
    return (j < 8) ? 8*g + j : 512 - 8*g - 15 + j;
}
__device__ __forceinline__ int jmir(int g, int j) {
    return (g == 0) ? ((16 - j) & 15) : (15 - j);
}

// ---- cols: fwd FFT along H, Hermitian mask-combine, inv FFT along H ----
// 512 thr, 16 cols/block, grid 2048, 77.8KB LDS -> 2 blk/CU (R4 footprint),
// 16 waves/CU (2x R4's 8).  Z I/O staged flat through LDS (4KB/column).
__global__ __launch_bounds__(512) void k_cols_pair(
        float2* __restrict__ Z,           // ZT [64][col][row], in place
        const float* __restrict__ mt)     // maskT2 [128][col][k]
{
    __shared__ float2 buf[16 * FS];       // 73,728 B
    __shared__ float2 tw[512];
    int t = threadIdx.x;
    build_tw<512>(tw, t);
    int c = t >> 5, w = t & 31;           // col c on threads [32c..32c+32)
    int p = blockIdx.x >> 5, g = blockIdx.x & 31;
    int colc = col_of(g, c);
    int cm   = jmir(g, c);
    size_t zch = (size_t)p * HW;
    const float* mAp = mt + (size_t)(2*p) * HW + (size_t)colc * 512;
    const float* mBp = mAp + HW;

    for (int it = 0; it < 16; ++it) {                 // flat stage-in: 4KB/column
        int n = t + 512*it;
        int cj = n >> 9, row = n & 511;
        buf[slotf(cj, row)] = Z[zch + (size_t)col_of(g, cj)*512 + row];
    }
    float Sa[2][8], Sb[2][8];
#pragma unroll
    for (int b = 0; b < 2; ++b) {                     // mask prefetch (hidden)
        int kb = dr6(w + 32*b);
#pragma unroll
        for (int m = 0; m < 8; ++m) {
            int k1 = kb + 64*m;
            Sa[b][m] = mAp[k1];
            Sb[b][m] = mBp[k1];
        }
    }
    __syncthreads();                                  // stage + tw ready

    float2 X[2][8];
#pragma unroll
    for (int b = 0; b < 2; ++b)
#pragma unroll
        for (int r = 0; r < 8; ++r)
            X[b][r] = buf[slotf(c, w + 32*b + 64*r)];
    wave_sync();                                      // own-row gather before E0 writes
    fft512_fwd<false>(X, buf, tw, w, c);

    wave_sync();                                      // own-row E1-reads done
#pragma unroll
    for (int b = 0; b < 2; ++b) {                     // publish spectra for mirror gather
        int kb = dr6(w + 32*b);
#pragma unroll
        for (int m = 0; m < 8; ++m) buf[slotf(c, kb + 64*m)] = X[b][m];
    }
    __syncthreads();                                  // mirror row is cross-wave

    const float s4 = 0.25f / 262144.0f;   // 1/4 combine * 1/N ifft scale
#pragma unroll
    for (int b = 0; b < 2; ++b) {
        int kb = dr6(w + 32*b);
#pragma unroll
        for (int m = 0; m < 8; ++m) {
            int k1  = kb + 64*m;
            int mk1 = (512 - k1) & 511;
            float2 P = X[b][m];
            float2 Q = buf[slotf(cm, mk1)];            // Zhat[-k1, -colc]
            float alpha = (Sa[b][m] + Sb[b][m]) * s4;
            float beta  = (Sa[b][m] - Sb[b][m]) * s4;
            X[b][m] = make_float2(alpha * P.x + beta * Q.x,
                                  alpha * P.y - beta * Q.y);
        }
    }
    __syncthreads();                                  // mirror reads of row c done
    fft512_inv<false>(X, buf, tw, w, c);
    wave_sync();                                      // own-row E0'-reads done
#pragma unroll
    for (int b = 0; b < 2; ++b)                       // publish natural for stage-out
#pragma unroll
        for (int r = 0; r < 8; ++r)
            buf[slotf(c, w + 32*b + 64*r)] = X[b][r];
    __syncthreads();                                  // cross-wave stage-out
    for (int it = 0; it < 16; ++it) {                 // flat stage-out: 4KB/column
        int n = t + 512*it;
        int cj = n >> 9, row = n & 511;
        Z[zch + (size_t)col_of(g, cj)*512 + row] = buf[slotf(cj, row)];
    }
}

// ---- rows inverse: ZT -> two real output channels (512 thr, 16 rows) ----
__global__ __launch_bounds__(512) void k_rows_inv_pair(
        const float2* __restrict__ Z,     // ZT [64][col][row]
        float* __restrict__ out)          // [128][512][512]
{
    __shared__ float2 buf[16 * FS];
    __shared__ float2 tw[512];
    int t = threadIdx.x;
    build_tw<512>(tw, t);
    int c = t >> 5, w = t & 31;
    int p = blockIdx.x >> 5, r0 = (blockIdx.x & 31) << 4;
    size_t zb = (size_t)p * HW + r0;

    for (int it = 0; it < 16; ++it) {                 // transposed stage-in: 128B/col
        int n = t + 512*it;
        int col = n >> 4, rr = n & 15;
        buf[slotf(rr, col)] = Z[zb + (size_t)col*512 + rr];
    }
    __syncthreads();                                  // stage + tw ready

    float2 X[2][8];
#pragma unroll
    for (int b = 0; b < 2; ++b) {                     // gather digit-rev residency
        int kb = dr6(w + 32*b);
#pragma unroll
        for (int m = 0; m < 8; ++m) X[b][m] = buf[slotf(c, kb + 64*m)];
    }
    fft512_inv<false>(X, buf, tw, w, c);              // internal wave_sync orders gather

    float* oA = out + (size_t)(2*p) * HW + (size_t)(r0 + c) * 512;
    float* oB = oA + HW;
#pragma unroll
    for (int b = 0; b < 2; ++b)
#pragma unroll
        for (int r = 0; r < 8; ++r) {
            int off = w + 32*b + 64*r;
            oA[off] = X[b][r].x;                      // direct, 128B/group
            oB[off] = X[b][r].y;
        }
}

// ---------------- launch ----------------

extern "C" void kernel_launch(void* const* d_in, const int* in_sizes, int n_in,
                              void* d_out, int out_size, void* d_ws, size_t ws_size,
                              hipStream_t stream) {
    const float* x    = (const float*)d_in[0];
    const float* cw   = (const float*)d_in[1];
    const float* cb   = (const float*)d_in[2];
    const float* mask = (const float*)d_in[3];

    float*  outRe = (float*)d_out;       // y -> maskT2 -> final out (time-sliced)
    float2* ZT    = (float2*)d_ws;       // transposed spectrum (134,217,728 B)

    // xt/wt occupy ws before ZT is first written (dead after conv).
    unsigned short* xt = (unsigned short*)d_ws;                       // 33,554,432 B
    unsigned short* wt = (unsigned short*)d_ws + (size_t)HW * 64;     //    147,456 B

    k_wprep<<<288, 256, 0, stream>>>(cw, wt);
    k_xprep<<<4096, 256, 0, stream>>>(x, xt);
    k_conv<<<2048, 512, 0, stream>>>(xt, wt, cb, outRe);
    k_rows_fwd_pair<<<2048, 512, 0, stream>>>(outRe, ZT);   // reads y, frees d_out
    k_maskT2<<<8192, 256, 0, stream>>>(mask, outRe);        // maskT2 into d_out
    k_cols_pair<<<2048, 512, 0, stream>>>(ZT, outRe);
    k_rows_inv_pair<<<2048, 512, 0, stream>>>(ZT, outRe);   // overwrites maskT2
}